// Round 2
// baseline (2967.274 us; speedup 1.0000x reference)
//
#include <hip/hip_runtime.h>
#include <hip/hip_bf16.h>

#define NH 4
#define DH 256
#define DMODEL 1024
#define BB 4
#define SS 2048

typedef __attribute__((ext_vector_type(4))) float f32x4;
typedef __attribute__((ext_vector_type(8))) short bf16x8;
typedef __attribute__((ext_vector_type(4))) int i32x4;

__device__ __forceinline__ int dot4i8(int acc, int a, int b) {
#if __has_builtin(__builtin_amdgcn_sdot4)
    return __builtin_amdgcn_sdot4(a, b, acc, false);
#else
#pragma unroll
    for (int i = 0; i < 4; ++i) {
        int av = (a << (24 - 8 * i)) >> 24;
        int bv = (b << (24 - 8 * i)) >> 24;
        acc += av * bv;
    }
    return acc;
#endif
}

// Raw workgroup barrier: orders LDS only; global loads/stores stay in flight.
__device__ __forceinline__ void wg_barrier() {
    asm volatile("s_waitcnt lgkmcnt(0)" ::: "memory");
    __builtin_amdgcn_s_barrier();
}

// quad butterfly sum via DPP (VALU, not LDS pipe). Exact integer adds.
__device__ __forceinline__ int quad_reduce_add(int v) {
    v += __builtin_amdgcn_update_dpp(0, v, 0xB1, 0xF, 0xF, true);  // + lane^1
    v += __builtin_amdgcn_update_dpp(0, v, 0x4E, 0xF, 0xF, true);  // + lane^2
    return v;
}

// ---------------- conv + swish ----------------
__global__ void k_conv(const float* __restrict__ x, const float* __restrict__ cw,
                       const float* __restrict__ cb, float* __restrict__ xc) {
    int bs = blockIdx.x;              // b*2048 + s
    int s = bs & (SS - 1);
    const float* xrow = x + (size_t)bs * DMODEL;
#pragma unroll
    for (int dd = 0; dd < 4; ++dd) {
        int d = threadIdx.x + dd * 256;
        float w0 = cw[d * 4 + 0], w1 = cw[d * 4 + 1], w2 = cw[d * 4 + 2], w3 = cw[d * 4 + 3];
        float acc = cb[d] + w3 * xrow[d];
        if (s >= 1) acc += w2 * xrow[d - DMODEL];
        if (s >= 2) acc += w1 * xrow[d - 2 * DMODEL];
        if (s >= 3) acc += w0 * xrow[d - 3 * DMODEL];
        float sig = 1.f / (1.f + __expf(-acc));
        xc[(size_t)bs * DMODEL + d] = acc * sig;
    }
}

// ---------------- headwise projections (bf16 MFMA GEMM) ----------------
// grid: (M/64=128, 512/64=8, 8 instances). instance z = h*2 + pair.
// pair0: {i,f} from x_conv ; pair1: {z,o} from x.
// gates layout: [b][h][s][g][d]  (coalesced epilogue writes)
__global__ void k_gemm(const float* __restrict__ x, const float* __restrict__ xc,
                       const float* __restrict__ wi, const float* __restrict__ wf,
                       const float* __restrict__ wz, const float* __restrict__ wo,
                       float* __restrict__ gates) {
    int h = blockIdx.z >> 1, pair = blockIdx.z & 1;
    const float* A = pair ? x : xc;
    int n0 = blockIdx.y * 64;  // in [0,512)
    const float* W = (n0 < 256) ? (pair ? wz : wi) : (pair ? wo : wf);
    int nl = n0 & 255;
    int m0 = blockIdx.x * 64;

    __shared__ __align__(16) __hip_bfloat16 Al[64][72];
    __shared__ __align__(16) __hip_bfloat16 Bl[64][72];

    int tid = threadIdx.x;
    int lane = tid & 63, wv = tid >> 6;
    f32x4 acc[4] = {};

    for (int k0 = 0; k0 < 256; k0 += 64) {
        __syncthreads();
#pragma unroll
        for (int i = 0; i < 4; ++i) {
            int f4 = tid + i * 256;
            int r = f4 >> 4, c4 = (f4 & 15) * 4;
            const float* srcA = A + (size_t)(m0 + r) * DMODEL + h * DH + k0 + c4;
            float4 v = *(const float4*)srcA;
            Al[r][c4 + 0] = __float2bfloat16(v.x);
            Al[r][c4 + 1] = __float2bfloat16(v.y);
            Al[r][c4 + 2] = __float2bfloat16(v.z);
            Al[r][c4 + 3] = __float2bfloat16(v.w);
            const float* srcB = W + (size_t)(h * DH + nl + r) * DH + k0 + c4;
            float4 u = *(const float4*)srcB;
            Bl[r][c4 + 0] = __float2bfloat16(u.x);
            Bl[r][c4 + 1] = __float2bfloat16(u.y);
            Bl[r][c4 + 2] = __float2bfloat16(u.z);
            Bl[r][c4 + 3] = __float2bfloat16(u.w);
        }
        __syncthreads();
#pragma unroll
        for (int kk = 0; kk < 64; kk += 32) {
            bf16x8 a = *(const bf16x8*)&Al[wv * 16 + (lane & 15)][kk + (lane >> 4) * 8];
#pragma unroll
            for (int nt = 0; nt < 4; ++nt) {
                bf16x8 bfr = *(const bf16x8*)&Bl[nt * 16 + (lane & 15)][kk + (lane >> 4) * 8];
                acc[nt] = __builtin_amdgcn_mfma_f32_16x16x32_bf16(a, bfr, acc[nt], 0, 0, 0);
            }
        }
    }
    // epilogue: gates[b][h][s][g][d]
#pragma unroll
    for (int nt = 0; nt < 4; ++nt)
#pragma unroll
        for (int r = 0; r < 4; ++r) {
            int m = m0 + wv * 16 + (lane >> 4) * 4 + r;
            int n = n0 + nt * 16 + (lane & 15);
            int b = m >> 11, s = m & (SS - 1);
            int g = pair * 2 + (n >> 8), d = n & 255;
            gates[((((size_t)(b * NH + h)) * SS + s) * 4 + g) * DH + d] = acc[nt][r];
        }
}

// ---------------- weight prep: per-column int8 quantization of R ----------------
__global__ void k_prep(const float* __restrict__ R, int* __restrict__ Wq,
                       float* __restrict__ scales) {
    int colid = blockIdx.x * 4 + (threadIdx.x >> 6);  // 0..4095
    int lane = threadIdx.x & 63;
    int h = colid >> 10, k = colid & 1023;
    const float* base = R + (size_t)h * 256 * 1024 + k;
    float v[4];
    float mx = 0.f;
#pragma unroll
    for (int i = 0; i < 4; ++i) {
        v[i] = base[(size_t)(lane * 4 + i) * 1024];
        mx = fmaxf(mx, fabsf(v[i]));
    }
    for (int off = 32; off; off >>= 1) mx = fmaxf(mx, __shfl_xor(mx, off));
    mx = fmaxf(mx, 1e-30f);
    float scale = mx * (1.f / 127.f);
    float inv = 127.f / mx;
    int pk = 0;
#pragma unroll
    for (int i = 0; i < 4; ++i) {
        int q = (int)rintf(v[i] * inv);
        q = max(-127, min(127, q));
        pk |= (q & 255) << (8 * i);
    }
    Wq[(h * 64 + lane) * 1024 + k] = pk;
    if (lane == 0) scales[h * 1024 + k] = scale;
}

// ---------------- the sequential sLSTM scan ----------------
// 16 blocks, one per (b,h). 1024 threads: thread t = (d = t>>2, q = t&3).
// Thread (d,q) computes K-quarter-q partials of the 4 gate columns {g*256+d},
// quad-reduces via DPP (in-register), then ALL quad lanes redundantly run the
// cell update for d. No rec[] LDS array, ONE barrier/step, hq double-buffered.
// __launch_bounds__(1024,1): only 16 blocks exist -> give allocator the full
// register budget so w[64] stays in VGPRs (no v_accvgpr_read per dot4).
__launch_bounds__(1024, 1)
__global__ void k_scan(const float* __restrict__ gates, const int* __restrict__ Wq,
                       const float* __restrict__ scales, const float* __restrict__ bias,
                       float* __restrict__ y) {
    int bh = blockIdx.x;
    int h = bh & 3;
    int t = threadIdx.x;
    int d = t >> 2, q = t & 3;

    __shared__ __align__(16) signed char hq[2][256];

    // w[g][j]: dword j of K-quarter q (input dims 4*(q*16+j)..+4), col g*256+d
    int w[4][16];
#pragma unroll
    for (int g = 0; g < 4; ++g)
#pragma unroll
        for (int j = 0; j < 16; ++j)
            w[g][j] = Wq[(h * 64 + q * 16 + j) * 1024 + g * 256 + d];

    float colmul[4];
#pragma unroll
    for (int g = 0; g < 4; ++g)
        colmul[g] = scales[h * 1024 + g * 256 + d] * (1.f / 127.f);

    float bi = bias[(0 * NH + h) * DH + d];
    float bf_ = bias[(1 * NH + h) * DH + d];
    float bz = bias[(2 * NH + h) * DH + d];
    float bo = bias[(3 * NH + h) * DH + d];

    float c = 0.f, n = 0.f, mstate = 0.f;
    const float* gbase = gates + (size_t)bh * SS * 1024 + d;
    float* ybase = y + (size_t)bh * SS * DH + d;

    if (t < 32) ((i32x4*)hq)[t] = (i32x4){0, 0, 0, 0};
    __syncthreads();

    // current-step gates in registers; prefetch distance 1
    float gcx = gbase[0], gcy = gbase[256], gcz = gbase[512], gcw = gbase[768];

    int p = 0;
    for (int s = 0; s < SS; ++s) {
        float gnx = gcx, gny = gcy, gnz = gcz, gnw = gcw;
        if (s + 1 < SS) {
            const float* gp = gbase + (size_t)(s + 1) * 1024;
            gnx = gp[0]; gny = gp[256]; gnz = gp[512]; gnw = gp[768];
        }

        // this thread's 64-byte slice of quantized h
        const i32x4* hv4 = (const i32x4*)hq[p];
        i32x4 h0 = hv4[q * 4 + 0];
        i32x4 h1 = hv4[q * 4 + 1];
        i32x4 h2 = hv4[q * 4 + 2];
        i32x4 h3 = hv4[q * 4 + 3];
        int hdw[16];
        hdw[0] = h0.x; hdw[1] = h0.y; hdw[2] = h0.z; hdw[3] = h0.w;
        hdw[4] = h1.x; hdw[5] = h1.y; hdw[6] = h1.z; hdw[7] = h1.w;
        hdw[8] = h2.x; hdw[9] = h2.y; hdw[10] = h2.z; hdw[11] = h2.w;
        hdw[12] = h3.x; hdw[13] = h3.y; hdw[14] = h3.z; hdw[15] = h3.w;

        int acc[4] = {0, 0, 0, 0};
#pragma unroll
        for (int g = 0; g < 4; ++g)
#pragma unroll
            for (int j = 0; j < 16; ++j)
                acc[g] = dot4i8(acc[g], w[g][j], hdw[j]);

        // quad reduction over K-quarters (exact int adds; all lanes get full sums)
        acc[0] = quad_reduce_add(acc[0]);
        acc[1] = quad_reduce_add(acc[1]);
        acc[2] = quad_reduce_add(acc[2]);
        acc[3] = quad_reduce_add(acc[3]);

        float ri = (float)acc[0] * colmul[0];
        float rf = (float)acc[1] * colmul[1];
        float rz = (float)acc[2] * colmul[2];
        float ro = (float)acc[3] * colmul[3];

        float rawi = gcx + ri + bi;
        float rawf = gcy + rf + bf_;
        float rawz = gcz + rz + bz;
        float rawo = gcw + ro + bo;
        // log_sigmoid(rawf) = min(rawf,0) - log1p(exp(-|rawf|))
        float lsf = fminf(rawf, 0.f) - __logf(1.f + __expf(-fabsf(rawf)));
        float lfm = mstate + lsf;
        float mn = fmaxf(rawi, lfm);
        float ig = __expf(rawi - mn);
        float fg = __expf(lfm - mn);
        float az = fabsf(rawz);
        float e2 = __expf(-2.f * az);
        float th = (1.f - e2) / (1.f + e2);
        th = rawz < 0.f ? -th : th;
        c = fg * c + ig * th;
        n = fg * n + ig;
        mstate = mn;
        float so = 1.f / (1.f + __expf(-rawo));
        float hv = so * c / n;

        if (q == 0) {
            ybase[(size_t)s * DH] = hv;
            hq[p ^ 1][d] = (signed char)(int)rintf(hv * 127.f);
        }

        gcx = gnx; gcy = gny; gcz = gnz; gcw = gnw;
        p ^= 1;
        wg_barrier();
    }
}

// ---------------- multihead layernorm + transpose ----------------
__global__ void k_ln(const float* __restrict__ y, const float* __restrict__ gsc,
                     const float* __restrict__ gbi, float* __restrict__ out) {
    int bid = blockIdx.x;  // bh*2048 + s
    int s = bid & (SS - 1);
    int bh = bid >> 11;
    int b = bh >> 2, h = bh & 3;
    int d = threadIdx.x;
    float v = y[(size_t)bid * DH + d];
    float s1 = v, s2 = v * v;
    for (int off = 32; off; off >>= 1) {
        s1 += __shfl_xor(s1, off);
        s2 += __shfl_xor(s2, off);
    }
    __shared__ float a1[4], a2[4];
    int wv = threadIdx.x >> 6, ln = threadIdx.x & 63;
    if (ln == 0) { a1[wv] = s1; a2[wv] = s2; }
    __syncthreads();
    s1 = a1[0] + a1[1] + a1[2] + a1[3];
    s2 = a2[0] + a2[1] + a2[2] + a2[3];
    float mu = s1 * (1.f / 256.f);
    float var = s2 * (1.f / 256.f) - mu * mu;
    float rs = rsqrtf(var + 1e-6f);
    float o = (v - mu) * rs * gsc[h * DH + d] + gbi[h * DH + d];
    out[((size_t)(b * SS + s)) * DMODEL + h * DH + d] = o;
}

extern "C" void kernel_launch(void* const* d_in, const int* in_sizes, int n_in,
                              void* d_out, int out_size, void* d_ws, size_t ws_size,
                              hipStream_t stream) {
    (void)in_sizes; (void)n_in; (void)out_size; (void)ws_size;
    const float* x = (const float*)d_in[0];
    const float* cw = (const float*)d_in[1];
    const float* cb = (const float*)d_in[2];
    const float* wi = (const float*)d_in[3];
    const float* wf = (const float*)d_in[4];
    const float* wz = (const float*)d_in[5];
    const float* wo = (const float*)d_in[6];
    const float* R = (const float*)d_in[7];
    const float* cbias = (const float*)d_in[8];
    const float* gsc = (const float*)d_in[9];
    const float* gbi = (const float*)d_in[10];
    float* out = (float*)d_out;

    char* ws = (char*)d_ws;
    float* xc = (float*)ws;                           // 33,554,432 B
    float* gates = (float*)(ws + 33554432ull);        // 134,217,728 B
    float* yb = (float*)(ws + 167772160ull);          // 33,554,432 B
    int* Wq = (int*)(ws + 201326592ull);              // 1,048,576 B
    float* scales = (float*)(ws + 202375168ull);      // 16,384 B

    k_prep<<<1024, 256, 0, stream>>>(R, Wq, scales);
    k_conv<<<BB * SS, 256, 0, stream>>>(x, cw, cb, xc);
    k_gemm<<<dim3(128, 8, 8), 256, 0, stream>>>(x, xc, wi, wf, wz, wo, gates);
    k_scan<<<16, 1024, 0, stream>>>(gates, Wq, scales, cbias, yb);
    k_ln<<<BB * SS * NH, 256, 0, stream>>>(yb, gsc, gbi, out);
}

// Round 3
// 2136.466 us; speedup vs baseline: 1.3889x; 1.3889x over previous
//
#include <hip/hip_runtime.h>
#include <hip/hip_bf16.h>

#define NH 4
#define DH 256
#define DMODEL 1024
#define BB 4
#define SS 2048

typedef __attribute__((ext_vector_type(4))) float f32x4;
typedef __attribute__((ext_vector_type(8))) short bf16x8;
typedef __attribute__((ext_vector_type(4))) int i32x4;

__device__ __forceinline__ int dot4i8(int acc, int a, int b) {
#if __has_builtin(__builtin_amdgcn_sdot4)
    return __builtin_amdgcn_sdot4(a, b, acc, false);
#else
#pragma unroll
    for (int i = 0; i < 4; ++i) {
        int av = (a << (24 - 8 * i)) >> 24;
        int bv = (b << (24 - 8 * i)) >> 24;
        acc += av * bv;
    }
    return acc;
#endif
}

// Raw workgroup barrier: orders LDS only; global loads/stores stay in flight.
__device__ __forceinline__ void wg_barrier() {
    asm volatile("s_waitcnt lgkmcnt(0)" ::: "memory");
    __builtin_amdgcn_s_barrier();
}

// exchange with lane^1 via DPP quad_perm (VALU pipe, not LDS)
__device__ __forceinline__ float xor1_f32(float v) {
    int r = __builtin_amdgcn_update_dpp(0, __float_as_int(v), 0xB1, 0xF, 0xF, true);
    return __int_as_float(r);
}

// ---------------- conv + swish ----------------
__global__ void k_conv(const float* __restrict__ x, const float* __restrict__ cw,
                       const float* __restrict__ cb, float* __restrict__ xc) {
    int bs = blockIdx.x;              // b*2048 + s
    int s = bs & (SS - 1);
    const float* xrow = x + (size_t)bs * DMODEL;
#pragma unroll
    for (int dd = 0; dd < 4; ++dd) {
        int d = threadIdx.x + dd * 256;
        float w0 = cw[d * 4 + 0], w1 = cw[d * 4 + 1], w2 = cw[d * 4 + 2], w3 = cw[d * 4 + 3];
        float acc = cb[d] + w3 * xrow[d];
        if (s >= 1) acc += w2 * xrow[d - DMODEL];
        if (s >= 2) acc += w1 * xrow[d - 2 * DMODEL];
        if (s >= 3) acc += w0 * xrow[d - 3 * DMODEL];
        float sig = 1.f / (1.f + __expf(-acc));
        xc[(size_t)bs * DMODEL + d] = acc * sig;
    }
}

// ---------------- headwise projections (bf16 MFMA GEMM) ----------------
// grid: (M/64=128, 512/64=8, 8 instances). instance z = h*2 + pair.
// pair0: {i,f} from x_conv ; pair1: {z,o} from x.
// gates layout: [b][h][s][g][d]  (coalesced epilogue writes)
__global__ void k_gemm(const float* __restrict__ x, const float* __restrict__ xc,
                       const float* __restrict__ wi, const float* __restrict__ wf,
                       const float* __restrict__ wz, const float* __restrict__ wo,
                       float* __restrict__ gates) {
    int h = blockIdx.z >> 1, pair = blockIdx.z & 1;
    const float* A = pair ? x : xc;
    int n0 = blockIdx.y * 64;  // in [0,512)
    const float* W = (n0 < 256) ? (pair ? wz : wi) : (pair ? wo : wf);
    int nl = n0 & 255;
    int m0 = blockIdx.x * 64;

    __shared__ __align__(16) __hip_bfloat16 Al[64][72];
    __shared__ __align__(16) __hip_bfloat16 Bl[64][72];

    int tid = threadIdx.x;
    int lane = tid & 63, wv = tid >> 6;
    f32x4 acc[4] = {};

    for (int k0 = 0; k0 < 256; k0 += 64) {
        __syncthreads();
#pragma unroll
        for (int i = 0; i < 4; ++i) {
            int f4 = tid + i * 256;
            int r = f4 >> 4, c4 = (f4 & 15) * 4;
            const float* srcA = A + (size_t)(m0 + r) * DMODEL + h * DH + k0 + c4;
            float4 v = *(const float4*)srcA;
            Al[r][c4 + 0] = __float2bfloat16(v.x);
            Al[r][c4 + 1] = __float2bfloat16(v.y);
            Al[r][c4 + 2] = __float2bfloat16(v.z);
            Al[r][c4 + 3] = __float2bfloat16(v.w);
            const float* srcB = W + (size_t)(h * DH + nl + r) * DH + k0 + c4;
            float4 u = *(const float4*)srcB;
            Bl[r][c4 + 0] = __float2bfloat16(u.x);
            Bl[r][c4 + 1] = __float2bfloat16(u.y);
            Bl[r][c4 + 2] = __float2bfloat16(u.z);
            Bl[r][c4 + 3] = __float2bfloat16(u.w);
        }
        __syncthreads();
#pragma unroll
        for (int kk = 0; kk < 64; kk += 32) {
            bf16x8 a = *(const bf16x8*)&Al[wv * 16 + (lane & 15)][kk + (lane >> 4) * 8];
#pragma unroll
            for (int nt = 0; nt < 4; ++nt) {
                bf16x8 bfr = *(const bf16x8*)&Bl[nt * 16 + (lane & 15)][kk + (lane >> 4) * 8];
                acc[nt] = __builtin_amdgcn_mfma_f32_16x16x32_bf16(a, bfr, acc[nt], 0, 0, 0);
            }
        }
    }
    // epilogue: gates[b][h][s][g][d]
#pragma unroll
    for (int nt = 0; nt < 4; ++nt)
#pragma unroll
        for (int r = 0; r < 4; ++r) {
            int m = m0 + wv * 16 + (lane >> 4) * 4 + r;
            int n = n0 + nt * 16 + (lane & 15);
            int b = m >> 11, s = m & (SS - 1);
            int g = pair * 2 + (n >> 8), d = n & 255;
            gates[((((size_t)(b * NH + h)) * SS + s) * 4 + g) * DH + d] = acc[nt][r];
        }
}

// ---------------- weight prep: per-column int8 quantization of R ----------------
__global__ void k_prep(const float* __restrict__ R, int* __restrict__ Wq,
                       float* __restrict__ scales) {
    int colid = blockIdx.x * 4 + (threadIdx.x >> 6);  // 0..4095
    int lane = threadIdx.x & 63;
    int h = colid >> 10, k = colid & 1023;
    const float* base = R + (size_t)h * 256 * 1024 + k;
    float v[4];
    float mx = 0.f;
#pragma unroll
    for (int i = 0; i < 4; ++i) {
        v[i] = base[(size_t)(lane * 4 + i) * 1024];
        mx = fmaxf(mx, fabsf(v[i]));
    }
    for (int off = 32; off; off >>= 1) mx = fmaxf(mx, __shfl_xor(mx, off));
    mx = fmaxf(mx, 1e-30f);
    float scale = mx * (1.f / 127.f);
    float inv = 127.f / mx;
    int pk = 0;
#pragma unroll
    for (int i = 0; i < 4; ++i) {
        int q = (int)rintf(v[i] * inv);
        q = max(-127, min(127, q));
        pk |= (q & 255) << (8 * i);
    }
    Wq[(h * 64 + lane) * 1024 + k] = pk;
    if (lane == 0) scales[h * 1024 + k] = scale;
}

// ---------------- the sequential sLSTM scan ----------------
// 16 blocks, one per (b,h). 512 threads: t = (d = t>>1, pair = t&1).
//   pair0 owns gate columns {i[d] (col d),   z[d] (col 512+d)}
//   pair1 owns gate columns {f[d] (col 256+d), o[d] (col 768+d)}
// Each thread holds its 2 weight columns int8-packed in 128 VGPRs. 512-thread
// blocks give 2 waves/SIMD -> 256-reg budget, so w[] stays in ARCH VGPRs
// (no v_accvgpr_read per dot4 — the round-0/1/2 hidden cost).
// Raw gate pre-activations exchanged lane<->lane^1 via one DPP each (VALU),
// both lanes run the cell redundantly: no rec[] LDS, ONE barrier per step.
// Gates prefetched at distance 2 via unroll-by-2 ping-pong registers.
__launch_bounds__(512, 2)
__global__ void k_scan(const float* __restrict__ gates, const int* __restrict__ Wq,
                       const float* __restrict__ scales, const float* __restrict__ bias,
                       float* __restrict__ y) {
    int bh = blockIdx.x;
    int h = bh & 3;
    int t = threadIdx.x;
    int d = t >> 1, pair = t & 1;

    __shared__ __align__(16) signed char hq[2][256];

    int col0 = pair * 256 + d;   // i[d] or f[d]
    int col1 = col0 + 512;       // z[d] or o[d]

    int w0[64], w1[64];
#pragma unroll
    for (int j = 0; j < 64; ++j) {
        w0[j] = Wq[(h * 64 + j) * 1024 + col0];
        w1[j] = Wq[(h * 64 + j) * 1024 + col1];
    }
    float cm0 = scales[h * 1024 + col0] * (1.f / 127.f);
    float cm1 = scales[h * 1024 + col1] * (1.f / 127.f);
    float b0 = bias[(pair * NH + h) * DH + d];        // bias i or f
    float b1 = bias[((2 + pair) * NH + h) * DH + d];  // bias z or o

    float c = 0.f, n = 0.f, mstate = 0.f;
    const float* gbase = gates + (size_t)bh * SS * 1024;
    float* ybase = y + (size_t)bh * SS * DH + d;

    if (t < 32) ((i32x4*)hq)[t] = (i32x4){0, 0, 0, 0};
    __syncthreads();

    // gate ping-pong: A = step s, B = step s+1 (distance-2 prefetch)
    float gA0 = gbase[col0], gA1 = gbase[col1];
    float gB0 = gbase[1024 + col0], gB1 = gbase[1024 + col1];

#define SCAN_STEP(P, G0, G1, SCUR)                                            \
    {                                                                          \
        int acc0 = 0, acc1 = 0;                                                \
        const i32x4* hv4 = (const i32x4*)hq[P];                                \
        _Pragma("unroll") for (int kb = 0; kb < 4; ++kb) {                     \
            i32x4 ha = hv4[kb * 4 + 0];                                        \
            i32x4 hb = hv4[kb * 4 + 1];                                        \
            i32x4 hc = hv4[kb * 4 + 2];                                        \
            i32x4 hd_ = hv4[kb * 4 + 3];                                       \
            int hd[16] = {ha.x, ha.y, ha.z, ha.w, hb.x, hb.y, hb.z, hb.w,      \
                          hc.x, hc.y, hc.z, hc.w, hd_.x, hd_.y, hd_.z, hd_.w}; \
            _Pragma("unroll") for (int j = 0; j < 16; ++j) {                   \
                acc0 = dot4i8(acc0, w0[kb * 16 + j], hd[j]);                   \
                acc1 = dot4i8(acc1, w1[kb * 16 + j], hd[j]);                   \
            }                                                                  \
        }                                                                      \
        float rawA = G0 + (float)acc0 * cm0 + b0;                              \
        float rawB = G1 + (float)acc1 * cm1 + b1;                              \
        int sp = (SCUR) + 2 < SS ? (SCUR) + 2 : SS - 1;                        \
        G0 = gbase[(size_t)sp * 1024 + col0];                                  \
        G1 = gbase[(size_t)sp * 1024 + col1];                                  \
        float recvA = xor1_f32(rawA);                                          \
        float recvB = xor1_f32(rawB);                                          \
        float rawi = pair ? recvA : rawA;                                      \
        float rawf = pair ? rawA : recvA;                                      \
        float rawz = pair ? recvB : rawB;                                      \
        float rawo = pair ? rawB : recvB;                                      \
        float lsf = fminf(rawf, 0.f) - __logf(1.f + __expf(-fabsf(rawf)));     \
        float lfm = mstate + lsf;                                              \
        float mn = fmaxf(rawi, lfm);                                           \
        float ig = __expf(rawi - mn);                                          \
        float fg = __expf(lfm - mn);                                           \
        float az = fabsf(rawz);                                                \
        float e2 = __expf(-2.f * az);                                          \
        float th = (1.f - e2) / (1.f + e2);                                    \
        th = rawz < 0.f ? -th : th;                                            \
        c = fg * c + ig * th;                                                  \
        n = fg * n + ig;                                                       \
        mstate = mn;                                                           \
        float so = 1.f / (1.f + __expf(-rawo));                                \
        float hv = so * c / n;                                                 \
        if (!pair) {                                                           \
            ybase[(size_t)(SCUR)*DH] = hv;                                     \
            hq[(P) ^ 1][d] = (signed char)(int)rintf(hv * 127.f);              \
        }                                                                      \
        wg_barrier();                                                          \
    }

    for (int s = 0; s < SS; s += 2) {
        SCAN_STEP(0, gA0, gA1, s)
        SCAN_STEP(1, gB0, gB1, s + 1)
    }
#undef SCAN_STEP
}

// ---------------- multihead layernorm + transpose ----------------
__global__ void k_ln(const float* __restrict__ y, const float* __restrict__ gsc,
                     const float* __restrict__ gbi, float* __restrict__ out) {
    int bid = blockIdx.x;  // bh*2048 + s
    int s = bid & (SS - 1);
    int bh = bid >> 11;
    int b = bh >> 2, h = bh & 3;
    int d = threadIdx.x;
    float v = y[(size_t)bid * DH + d];
    float s1 = v, s2 = v * v;
    for (int off = 32; off; off >>= 1) {
        s1 += __shfl_xor(s1, off);
        s2 += __shfl_xor(s2, off);
    }
    __shared__ float a1[4], a2[4];
    int wv = threadIdx.x >> 6, ln = threadIdx.x & 63;
    if (ln == 0) { a1[wv] = s1; a2[wv] = s2; }
    __syncthreads();
    s1 = a1[0] + a1[1] + a1[2] + a1[3];
    s2 = a2[0] + a2[1] + a2[2] + a2[3];
    float mu = s1 * (1.f / 256.f);
    float var = s2 * (1.f / 256.f) - mu * mu;
    float rs = rsqrtf(var + 1e-6f);
    float o = (v - mu) * rs * gsc[h * DH + d] + gbi[h * DH + d];
    out[((size_t)(b * SS + s)) * DMODEL + h * DH + d] = o;
}

extern "C" void kernel_launch(void* const* d_in, const int* in_sizes, int n_in,
                              void* d_out, int out_size, void* d_ws, size_t ws_size,
                              hipStream_t stream) {
    (void)in_sizes; (void)n_in; (void)out_size; (void)ws_size;
    const float* x = (const float*)d_in[0];
    const float* cw = (const float*)d_in[1];
    const float* cb = (const float*)d_in[2];
    const float* wi = (const float*)d_in[3];
    const float* wf = (const float*)d_in[4];
    const float* wz = (const float*)d_in[5];
    const float* wo = (const float*)d_in[6];
    const float* R = (const float*)d_in[7];
    const float* cbias = (const float*)d_in[8];
    const float* gsc = (const float*)d_in[9];
    const float* gbi = (const float*)d_in[10];
    float* out = (float*)d_out;

    char* ws = (char*)d_ws;
    float* xc = (float*)ws;                           // 33,554,432 B
    float* gates = (float*)(ws + 33554432ull);        // 134,217,728 B
    float* yb = (float*)(ws + 167772160ull);          // 33,554,432 B
    int* Wq = (int*)(ws + 201326592ull);              // 1,048,576 B
    float* scales = (float*)(ws + 202375168ull);      // 16,384 B

    k_prep<<<1024, 256, 0, stream>>>(R, Wq, scales);
    k_conv<<<BB * SS, 256, 0, stream>>>(x, cw, cb, xc);
    k_gemm<<<dim3(128, 8, 8), 256, 0, stream>>>(x, xc, wi, wf, wz, wo, gates);
    k_scan<<<16, 512, 0, stream>>>(gates, Wq, scales, cbias, yb);
    k_ln<<<BB * SS * NH, 256, 0, stream>>>(yb, gsc, gbi, out);
}

// Round 4
// 2078.615 us; speedup vs baseline: 1.4275x; 1.0278x over previous
//
#include <hip/hip_runtime.h>
#include <hip/hip_bf16.h>

#define NH 4
#define DH 256
#define DMODEL 1024
#define BB 4
#define SS 2048

typedef __attribute__((ext_vector_type(4))) float f32x4;
typedef __attribute__((ext_vector_type(8))) short bf16x8;
typedef __attribute__((ext_vector_type(4))) int i32x4;

// Raw workgroup barrier: orders LDS only; global loads/stores stay in flight.
__device__ __forceinline__ void wg_barrier() {
    asm volatile("s_waitcnt lgkmcnt(0)" ::: "memory");
    __builtin_amdgcn_s_barrier();
    __builtin_amdgcn_sched_barrier(0);
}

// ---------------- conv + swish ----------------
__global__ void k_conv(const float* __restrict__ x, const float* __restrict__ cw,
                       const float* __restrict__ cb, float* __restrict__ xc) {
    int bs = blockIdx.x;              // b*2048 + s
    int s = bs & (SS - 1);
    const float* xrow = x + (size_t)bs * DMODEL;
#pragma unroll
    for (int dd = 0; dd < 4; ++dd) {
        int d = threadIdx.x + dd * 256;
        float w0 = cw[d * 4 + 0], w1 = cw[d * 4 + 1], w2 = cw[d * 4 + 2], w3 = cw[d * 4 + 3];
        float acc = cb[d] + w3 * xrow[d];
        if (s >= 1) acc += w2 * xrow[d - DMODEL];
        if (s >= 2) acc += w1 * xrow[d - 2 * DMODEL];
        if (s >= 3) acc += w0 * xrow[d - 3 * DMODEL];
        float sig = 1.f / (1.f + __expf(-acc));
        xc[(size_t)bs * DMODEL + d] = acc * sig;
    }
}

// ---------------- headwise projections (bf16 MFMA GEMM) ----------------
// grid: (M/64=128, 512/64=8, 8 instances). instance z = h*2 + pair.
// pair0: {i,f} from x_conv ; pair1: {z,o} from x.
// gates layout: [b][h][s][g][d]  (coalesced epilogue writes)
__global__ void k_gemm(const float* __restrict__ x, const float* __restrict__ xc,
                       const float* __restrict__ wi, const float* __restrict__ wf,
                       const float* __restrict__ wz, const float* __restrict__ wo,
                       float* __restrict__ gates) {
    int h = blockIdx.z >> 1, pair = blockIdx.z & 1;
    const float* A = pair ? x : xc;
    int n0 = blockIdx.y * 64;  // in [0,512)
    const float* W = (n0 < 256) ? (pair ? wz : wi) : (pair ? wo : wf);
    int nl = n0 & 255;
    int m0 = blockIdx.x * 64;

    __shared__ __align__(16) __hip_bfloat16 Al[64][72];
    __shared__ __align__(16) __hip_bfloat16 Bl[64][72];

    int tid = threadIdx.x;
    int lane = tid & 63, wv = tid >> 6;
    f32x4 acc[4] = {};

    for (int k0 = 0; k0 < 256; k0 += 64) {
        __syncthreads();
#pragma unroll
        for (int i = 0; i < 4; ++i) {
            int f4 = tid + i * 256;
            int r = f4 >> 4, c4 = (f4 & 15) * 4;
            const float* srcA = A + (size_t)(m0 + r) * DMODEL + h * DH + k0 + c4;
            float4 v = *(const float4*)srcA;
            Al[r][c4 + 0] = __float2bfloat16(v.x);
            Al[r][c4 + 1] = __float2bfloat16(v.y);
            Al[r][c4 + 2] = __float2bfloat16(v.z);
            Al[r][c4 + 3] = __float2bfloat16(v.w);
            const float* srcB = W + (size_t)(h * DH + nl + r) * DH + k0 + c4;
            float4 u = *(const float4*)srcB;
            Bl[r][c4 + 0] = __float2bfloat16(u.x);
            Bl[r][c4 + 1] = __float2bfloat16(u.y);
            Bl[r][c4 + 2] = __float2bfloat16(u.z);
            Bl[r][c4 + 3] = __float2bfloat16(u.w);
        }
        __syncthreads();
#pragma unroll
        for (int kk = 0; kk < 64; kk += 32) {
            bf16x8 a = *(const bf16x8*)&Al[wv * 16 + (lane & 15)][kk + (lane >> 4) * 8];
#pragma unroll
            for (int nt = 0; nt < 4; ++nt) {
                bf16x8 bfr = *(const bf16x8*)&Bl[nt * 16 + (lane & 15)][kk + (lane >> 4) * 8];
                acc[nt] = __builtin_amdgcn_mfma_f32_16x16x32_bf16(a, bfr, acc[nt], 0, 0, 0);
            }
        }
    }
    // epilogue: gates[b][h][s][g][d]
#pragma unroll
    for (int nt = 0; nt < 4; ++nt)
#pragma unroll
        for (int r = 0; r < 4; ++r) {
            int m = m0 + wv * 16 + (lane >> 4) * 4 + r;
            int n = n0 + nt * 16 + (lane & 15);
            int b = m >> 11, s = m & (SS - 1);
            int g = pair * 2 + (n >> 8), d = n & 255;
            gates[((((size_t)(b * NH + h)) * SS + s) * 4 + g) * DH + d] = acc[nt][r];
        }
}

// ---------------- weight prep: per-column int8 quantization of R ----------------
// Wq[(h*64 + j)*1024 + col]: 4 i8 packed (byte i = R[h][4j+i][col] quantized)
__global__ void k_prep(const float* __restrict__ R, int* __restrict__ Wq,
                       float* __restrict__ scales) {
    int colid = blockIdx.x * 4 + (threadIdx.x >> 6);  // 0..4095
    int lane = threadIdx.x & 63;
    int h = colid >> 10, k = colid & 1023;
    const float* base = R + (size_t)h * 256 * 1024 + k;
    float v[4];
    float mx = 0.f;
#pragma unroll
    for (int i = 0; i < 4; ++i) {
        v[i] = base[(size_t)(lane * 4 + i) * 1024];
        mx = fmaxf(mx, fabsf(v[i]));
    }
    for (int off = 32; off; off >>= 1) mx = fmaxf(mx, __shfl_xor(mx, off));
    mx = fmaxf(mx, 1e-30f);
    float scale = mx * (1.f / 127.f);
    float inv = 127.f / mx;
    int pk = 0;
#pragma unroll
    for (int i = 0; i < 4; ++i) {
        int q = (int)rintf(v[i] * inv);
        q = max(-127, min(127, q));
        pk |= (q & 255) << (8 * i);
    }
    Wq[(h * 64 + lane) * 1024 + k] = pk;
    if (lane == 0) scales[h * 1024 + k] = scale;
}

// ---------------- the sequential sLSTM scan (i8 MFMA recurrence) ----------------
// 16 blocks, one per (b,h). 512 threads = 8 waves; wave wv owns output-col
// tiles T = wv*8 .. wv*8+7 (16 cols each; 1024 cols = 4 gates x 256 d).
// Per step: rec = h(i8,256) x Rq(i8,256x1024) on the MATRIX pipe via
// mfma_i32_16x16x64_i8. B-fragments (weights) live in AGPR/VGPR and feed MFMA
// directly -- this sidesteps the v_accvgpr_read-per-dot tax that capped rounds
// 0-3 (v_dot4 cannot source AGPRs; MFMA can). A-operand = hq broadcast from
// LDS (identical for all 16 rows -> row 0 of D is the exact integer dot).
// rec handed to 256 cell threads via LDS (int32), cell math unchanged.
__launch_bounds__(512, 2)
__global__ void k_scan(const float* __restrict__ gates, const int* __restrict__ Wq,
                       const float* __restrict__ scales, const float* __restrict__ bias,
                       float* __restrict__ y) {
    int bh = blockIdx.x;
    int h = bh & 3;
    int t = threadIdx.x;
    int lane = t & 63;
    int wv = t >> 6;        // wave 0..7
    int kg = lane >> 4;     // K-group 0..3 within a fragment
    int cl = lane & 15;     // col-within-tile

    __shared__ __align__(16) signed char hq[256];
    __shared__ __align__(16) int rec_i[DH * 4];   // [d][g] raw int32 sums

    // ---- B fragments: [tile][K-chunk], 16 i8 per lane per fragment.
    // frag dword j4 = Wq[(h*64 + c*16 + kg*4 + j4)*1024 + col]  (k = c*64+kg*16+4*j4+{0..3})
    i32x4 bfr[8][4];
#pragma unroll
    for (int tt = 0; tt < 8; ++tt) {
        int col = (wv * 8 + tt) * 16 + cl;
#pragma unroll
        for (int c = 0; c < 4; ++c)
#pragma unroll
            for (int j4 = 0; j4 < 4; ++j4)
                bfr[tt][c][j4] = Wq[(h * 64 + c * 16 + kg * 4 + j4) * 1024 + col];
    }

    // rec_i byte addresses for D row-0 writes (lanes 0..15): col=(wv*8+tt)*16+lane
    int raddr[8];
#pragma unroll
    for (int tt = 0; tt < 8; ++tt) {
        int col = (wv * 8 + tt) * 16 + lane;
        raddr[tt] = ((col & 255) * 4 + (col >> 8)) * 4;
    }

    i32x4 acc[8];
#pragma unroll
    for (int tt = 0; tt < 8; ++tt) acc[tt] = (i32x4){0, 0, 0, 0};

    // ---- cell-thread state (t < 256; d = t)
    int d = t;
    float cm0 = 0, cm1 = 0, cm2 = 0, cm3 = 0, bi = 0, bf_ = 0, bz = 0, bo = 0;
    const float* gbase = gates + (size_t)bh * SS * 1024;
    float* ybase = y + (size_t)bh * SS * DH;
    if (t < 256) {
        cm0 = scales[h * 1024 + d] * (1.f / 127.f);
        cm1 = scales[h * 1024 + 256 + d] * (1.f / 127.f);
        cm2 = scales[h * 1024 + 512 + d] * (1.f / 127.f);
        cm3 = scales[h * 1024 + 768 + d] * (1.f / 127.f);
        bi = bias[(0 * NH + h) * DH + d];
        bf_ = bias[(1 * NH + h) * DH + d];
        bz = bias[(2 * NH + h) * DH + d];
        bo = bias[(3 * NH + h) * DH + d];
    }
    float c_ = 0.f, n_ = 0.f, mstate = 0.f;

    if (t < 16) ((i32x4*)hq)[t] = (i32x4){0, 0, 0, 0};
    __syncthreads();

    // gate ping-pong (distance-2 prefetch, rides under MFMA + barriers)
    float gA0 = 0, gA1 = 0, gA2 = 0, gA3 = 0, gB0 = 0, gB1 = 0, gB2 = 0, gB3 = 0;
    if (t < 256) {
        gA0 = gbase[d]; gA1 = gbase[256 + d]; gA2 = gbase[512 + d]; gA3 = gbase[768 + d];
        gB0 = gbase[1024 + d]; gB1 = gbase[1024 + 256 + d];
        gB2 = gbase[1024 + 512 + d]; gB3 = gbase[1024 + 768 + d];
    }

    const i32x4* hp = (const i32x4*)hq;
    const i32x4* rp = (const i32x4*)rec_i;

#define SCAN_STEP(SCUR, G0, G1, G2, G3)                                        \
    {                                                                          \
        float p0 = 0, p1 = 0, p2 = 0, p3 = 0;                                  \
        if (t < 256) {                                                         \
            int sp = (SCUR) + 2 < SS ? (SCUR) + 2 : SS - 1;                    \
            const float* gp = gbase + (size_t)sp * 1024 + d;                   \
            p0 = gp[0]; p1 = gp[256]; p2 = gp[512]; p3 = gp[768];              \
        }                                                                      \
        /* A fragments: broadcast h (identical for all 16 rows) */             \
        i32x4 a0 = hp[kg], a1 = hp[4 + kg], a2 = hp[8 + kg], a3 = hp[12 + kg]; \
        _Pragma("unroll") for (int tt = 0; tt < 8; ++tt) acc[tt].x = 0;        \
        _Pragma("unroll") for (int tt = 0; tt < 8; ++tt)                       \
            acc[tt] = __builtin_amdgcn_mfma_i32_16x16x64_i8(a0, bfr[tt][0], acc[tt], 0, 0, 0); \
        _Pragma("unroll") for (int tt = 0; tt < 8; ++tt)                       \
            acc[tt] = __builtin_amdgcn_mfma_i32_16x16x64_i8(a1, bfr[tt][1], acc[tt], 0, 0, 0); \
        _Pragma("unroll") for (int tt = 0; tt < 8; ++tt)                       \
            acc[tt] = __builtin_amdgcn_mfma_i32_16x16x64_i8(a2, bfr[tt][2], acc[tt], 0, 0, 0); \
        _Pragma("unroll") for (int tt = 0; tt < 8; ++tt)                       \
            acc[tt] = __builtin_amdgcn_mfma_i32_16x16x64_i8(a3, bfr[tt][3], acc[tt], 0, 0, 0); \
        if (lane < 16) {                                                       \
            _Pragma("unroll") for (int tt = 0; tt < 8; ++tt)                   \
                *(int*)((char*)rec_i + raddr[tt]) = acc[tt].x;                 \
        }                                                                      \
        wg_barrier();                                                          \
        if (t < 256) {                                                         \
            i32x4 r4 = rp[d];                                                  \
            float rawi = (G0) + (float)r4.x * cm0 + bi;                        \
            float rawf = (G1) + (float)r4.y * cm1 + bf_;                       \
            float rawz = (G2) + (float)r4.z * cm2 + bz;                        \
            float rawo = (G3) + (float)r4.w * cm3 + bo;                        \
            float lsf = fminf(rawf, 0.f) - __logf(1.f + __expf(-fabsf(rawf))); \
            float lfm = mstate + lsf;                                          \
            float mn = fmaxf(rawi, lfm);                                       \
            float ig = __expf(rawi - mn);                                      \
            float fg = __expf(lfm - mn);                                       \
            float az = fabsf(rawz);                                            \
            float e2 = __expf(-2.f * az);                                      \
            float th = (1.f - e2) / (1.f + e2);                                \
            th = rawz < 0.f ? -th : th;                                        \
            c_ = fg * c_ + ig * th;                                            \
            n_ = fg * n_ + ig;                                                 \
            mstate = mn;                                                       \
            float so = 1.f / (1.f + __expf(-rawo));                            \
            float hv = so * c_ / n_;                                           \
            ybase[(size_t)(SCUR)*DH + d] = hv;                                 \
            hq[d] = (signed char)(int)rintf(hv * 127.f);                       \
        }                                                                      \
        G0 = p0; G1 = p1; G2 = p2; G3 = p3;                                    \
        wg_barrier();                                                          \
    }

    for (int s = 0; s < SS; s += 2) {
        SCAN_STEP(s, gA0, gA1, gA2, gA3)
        SCAN_STEP(s + 1, gB0, gB1, gB2, gB3)
    }
#undef SCAN_STEP
}

// ---------------- multihead layernorm + transpose ----------------
__global__ void k_ln(const float* __restrict__ y, const float* __restrict__ gsc,
                     const float* __restrict__ gbi, float* __restrict__ out) {
    int bid = blockIdx.x;  // bh*2048 + s
    int s = bid & (SS - 1);
    int bh = bid >> 11;
    int b = bh >> 2, h = bh & 3;
    int d = threadIdx.x;
    float v = y[(size_t)bid * DH + d];
    float s1 = v, s2 = v * v;
    for (int off = 32; off; off >>= 1) {
        s1 += __shfl_xor(s1, off);
        s2 += __shfl_xor(s2, off);
    }
    __shared__ float a1[4], a2[4];
    int wv = threadIdx.x >> 6, ln = threadIdx.x & 63;
    if (ln == 0) { a1[wv] = s1; a2[wv] = s2; }
    __syncthreads();
    s1 = a1[0] + a1[1] + a1[2] + a1[3];
    s2 = a2[0] + a2[1] + a2[2] + a2[3];
    float mu = s1 * (1.f / 256.f);
    float var = s2 * (1.f / 256.f) - mu * mu;
    float rs = rsqrtf(var + 1e-6f);
    float o = (v - mu) * rs * gsc[h * DH + d] + gbi[h * DH + d];
    out[((size_t)(b * SS + s)) * DMODEL + h * DH + d] = o;
}

extern "C" void kernel_launch(void* const* d_in, const int* in_sizes, int n_in,
                              void* d_out, int out_size, void* d_ws, size_t ws_size,
                              hipStream_t stream) {
    (void)in_sizes; (void)n_in; (void)out_size; (void)ws_size;
    const float* x = (const float*)d_in[0];
    const float* cw = (const float*)d_in[1];
    const float* cb = (const float*)d_in[2];
    const float* wi = (const float*)d_in[3];
    const float* wf = (const float*)d_in[4];
    const float* wz = (const float*)d_in[5];
    const float* wo = (const float*)d_in[6];
    const float* R = (const float*)d_in[7];
    const float* cbias = (const float*)d_in[8];
    const float* gsc = (const float*)d_in[9];
    const float* gbi = (const float*)d_in[10];
    float* out = (float*)d_out;

    char* ws = (char*)d_ws;
    float* xc = (float*)ws;                           // 33,554,432 B
    float* gates = (float*)(ws + 33554432ull);        // 134,217,728 B
    float* yb = (float*)(ws + 167772160ull);          // 33,554,432 B
    int* Wq = (int*)(ws + 201326592ull);              // 1,048,576 B
    float* scales = (float*)(ws + 202375168ull);      // 16,384 B

    k_prep<<<1024, 256, 0, stream>>>(R, Wq, scales);
    k_conv<<<BB * SS, 256, 0, stream>>>(x, cw, cb, xc);
    k_gemm<<<dim3(128, 8, 8), 256, 0, stream>>>(x, xc, wi, wf, wz, wo, gates);
    k_scan<<<16, 512, 0, stream>>>(gates, Wq, scales, cbias, yb);
    k_ln<<<BB * SS * NH, 256, 0, stream>>>(yb, gsc, gbi, out);
}